// Round 15
// baseline (1076.004 us; speedup 1.0000x reference)
//
#include <hip/hip_runtime.h>
#include <stdint.h>

#define KCODES 8192
#define DIM 256
#define BN 128              // rescan col tile
#define NKT (KCODES / BN)

typedef _Float16 h16;
typedef __attribute__((ext_vector_type(8))) _Float16 f16x8;
typedef __attribute__((ext_vector_type(4))) float f32x4;

__device__ __forceinline__ void split8(const float* __restrict__ x, f16x8& h, f16x8& l) {
    #pragma unroll
    for (int i = 0; i < 8; ++i) {
        float v = x[i];
        _Float16 hv = (_Float16)v;          // RNE
        h[i] = hv;
        l[i] = (_Float16)(v - (float)hv);   // exact residual in f32, RNE to f16
    }
}

__device__ __forceinline__ unsigned int ford(float f) {   // monotone float->uint
    unsigned int b = __float_as_uint(f);
    return (b & 0x80000000u) ? ~b : (b | 0x80000000u);
}

// ---- ws layout (bytes); ws >= 8.4 MB (proven R5-R14) ----
#define WS_C2H   0u
#define WS_LC    32768u
#define WS_CN    65536u
#define WS_CNT   98304u      // int cnt; +4: u32 gmaxLC; +8: u32 gmaxCN
#define WS_LIST  98560u
#define WS_CAND  360704u
#define WS_THR   622848u
#define WS_KEYS  917504u
#define WS_BPH   2097152u    // 4 MB lane-ordered h-only image (ends at 6 MB)

// ---------------- prep: c2h, lc, cn per code + global maxima ----------------
__global__ __launch_bounds__(256) void c2x_kernel(const float* __restrict__ cb,
                                                  float* __restrict__ c2h,
                                                  float* __restrict__ lc,
                                                  float* __restrict__ cn,
                                                  unsigned int* __restrict__ gmx,
                                                  int K) {
    int w = (blockIdx.x * blockDim.x + threadIdx.x) >> 6;
    int lane = threadIdx.x & 63;
    if (w >= K) return;
    const float4 v = *(const float4*)(cb + (size_t)w * DIM + lane * 4);
    float s = 0.f, sr = 0.f;
    const float xs[4] = {v.x, v.y, v.z, v.w};
    #pragma unroll
    for (int i = 0; i < 4; ++i) {
        float x = xs[i];
        s += x * x;
        float hf = (float)(_Float16)x;
        float rho = x - hf;
        sr += rho * rho;
    }
    #pragma unroll
    for (int off = 32; off > 0; off >>= 1) { s += __shfl_down(s, off); sr += __shfl_down(sr, off); }
    if (lane == 0) {
        float sn = sqrtf(s), srn = sqrtf(sr);
        c2h[w] = 0.5f * s; cn[w] = sn; lc[w] = srn;
        atomicMax(&gmx[0], __float_as_uint(srn));   // positive floats: bits monotone
        atomicMax(&gmx[1], __float_as_uint(sn));
    }
}

// ---------------- pack: lane-ordered h-only image ----------------
// Frag (ct 0..255, ch 0..7, n 0..1) = 1 KB at (ct*8+ch)*2048B + n*1024B;
// lane l = g*16+c15 holds 16 B = h of code (ct*32 + n*16 + c15),
// d = ch*32 + g*8 .. +7. Matches the A-frag lane map (k-perm safe).
__global__ __launch_bounds__(256) void pack_h2_kernel(const float* __restrict__ cb,
                                                      h16* __restrict__ Bp) {
    const int tid = blockIdx.x * 256 + threadIdx.x;   // 8192*32
    const int code = tid >> 5;
    const int grp = tid & 31;                         // 8-d group
    float x[8];
    *(float4*)&x[0] = *(const float4*)(cb + (size_t)code * DIM + grp * 8);
    *(float4*)&x[4] = *(const float4*)(cb + (size_t)code * DIM + grp * 8 + 4);
    f16x8 hh;
    #pragma unroll
    for (int i = 0; i < 8; ++i) hh[i] = (_Float16)x[i];
    const int ct = code >> 5;
    const int n = (code >> 4) & 1;
    const int cc = code & 15;
    const int ch = grp >> 2, g = grp & 3;
    *(f16x8*)(Bp + (size_t)(ct * 8 + ch) * 1024 + n * 512 + (g * 16 + cc) * 8) = hh;
}

// ---------------- pass 1: barrier-free hh scores + per-row top-2 bound -------
// Wave = 32 rows (m=2, A in regs) x col-quarter (2048 codes). Per step
// (ct,ch): 2 coalesced dwordx4 B-loads -> regs, 4 MFMA. No LDS staging,
// no barriers. Final cross-wave quarter-merge via 1.5 KB LDS.
__global__ __launch_bounds__(256, 3) void vq_pass1(
    const float* __restrict__ rep, const h16* __restrict__ Bp,
    const float* __restrict__ c2h, const unsigned int* __restrict__ gmx,
    int* __restrict__ cand, float* __restrict__ thr) {

    __shared__ float sv1[32][4];
    __shared__ int si1[32][4];
    __shared__ float sv2[32][4];

    const int t = threadIdx.x;
    const int lane = t & 63;
    const int c15 = lane & 15;
    const int g = lane >> 4;
    const int q = t >> 6;                 // wave = col-quarter 0..3
    const int row0 = blockIdx.x * 32;

    const float Lmax = __uint_as_float(gmx[0]);
    const float Cmax = __uint_as_float(gmx[1]);

    // ---- A: h fragments + row-correct bound U[m][r] (R14-proven math) ----
    f16x8 ah[2][8];
    float U[2][4];
    #pragma unroll
    for (int m = 0; m < 2; ++m) {
        const float* ar = rep + (size_t)(row0 + m * 16 + c15) * DIM + g * 8;
        float hs = 0.f, rs = 0.f;
        #pragma unroll
        for (int ch = 0; ch < 8; ++ch) {
            float x[8];
            *(float4*)&x[0] = *(const float4*)(ar + ch * 32);
            *(float4*)&x[4] = *(const float4*)(ar + ch * 32 + 4);
            #pragma unroll
            for (int i = 0; i < 8; ++i) {
                _Float16 hv = (_Float16)x[i];
                ah[m][ch][i] = hv;
                float hf = (float)hv;
                hs += hf * hf;
                float rho = x[i] - hf;
                rs += rho * rho;
            }
        }
        hs += __shfl_xor(hs, 16); hs += __shfl_xor(hs, 32);
        rs += __shfl_xor(rs, 16); rs += __shfl_xor(rs, 32);
        float hn = sqrtf(hs), rn = sqrtf(rs);
        #pragma unroll
        for (int r = 0; r < 4; ++r) {
            float hnr = __shfl(hn, g * 4 + r);
            float rnr = __shfl(rn, g * 4 + r);
            U[m][r] = fmaf(hnr, Lmax, fmaf(rnr, Cmax, 0.012f));
        }
    }

    f32x4 acc[2][2];
    float u1v[2][4], u2v[2][4];
    int u1i[2][4];
    #pragma unroll
    for (int m = 0; m < 2; ++m)
        #pragma unroll
        for (int r = 0; r < 4; ++r) { u1v[m][r] = -3.4e38f; u2v[m][r] = -3.4e38f; u1i[m][r] = 0; }

    const h16* bq = Bp + (size_t)q * 64 * 8192;   // quarter base (64 ct x 8 ch x 1024 h16)

    // register double-buffer, static after full unroll of ch
    f16x8 bb[2][2];
    bb[0][0] = *(const f16x8*)(bq + lane * 8);
    bb[0][1] = *(const f16x8*)(bq + 512 + lane * 8);

    #pragma unroll 1
    for (int lt = 0; lt < 64; ++lt) {
        const int ct = q * 64 + lt;
        const int colb = ct * 32;
        const float D0 = c2h[colb + c15];         // used after 8 steps - hidden
        const float D1 = c2h[colb + 16 + c15];
        const h16* cbase = bq + (size_t)lt * 8192;
        #pragma unroll
        for (int m = 0; m < 2; ++m)
            #pragma unroll
            for (int n = 0; n < 2; ++n)
                #pragma unroll
                for (int r = 0; r < 4; ++r) acc[m][n][r] = U[m][r];

        #pragma unroll
        for (int ch = 0; ch < 8; ++ch) {
            const int cur = ch & 1;
            // prefetch next frag (next ch, or next ct's ch0; last is a dead
            // in-bounds load - image is followed by >2 MB of ws)
            const h16* nx = (ch < 7) ? cbase + (ch + 1) * 1024 : cbase + 8192;
            bb[cur ^ 1][0] = *(const f16x8*)(nx + lane * 8);
            bb[cur ^ 1][1] = *(const f16x8*)(nx + 512 + lane * 8);
            #pragma unroll
            for (int n = 0; n < 2; ++n)
                #pragma unroll
                for (int m = 0; m < 2; ++m)
                    acc[m][n] = __builtin_amdgcn_mfma_f32_16x16x32_f16(ah[m][ch], bb[cur][n], acc[m][n], 0, 0, 0);
        }

        // epilogue: u = acc - c2h; strict '>' + ascending cols = np tie rule
        #pragma unroll
        for (int n = 0; n < 2; ++n) {
            const float Dn = n ? D1 : D0;
            const int col = colb + n * 16 + c15;
            #pragma unroll
            for (int m = 0; m < 2; ++m)
                #pragma unroll
                for (int r = 0; r < 4; ++r) {
                    float u = acc[m][n][r] - Dn;
                    if (u > u1v[m][r]) { u2v[m][r] = u1v[m][r]; u1v[m][r] = u; u1i[m][r] = col; }
                    else if (u > u2v[m][r]) u2v[m][r] = u;
                }
        }
    }

    // ---- in-wave top-2 merge across the 16 c15-lanes ----
    #pragma unroll
    for (int m = 0; m < 2; ++m)
        #pragma unroll
        for (int r = 0; r < 4; ++r) {
            float a1 = u1v[m][r], a2 = u2v[m][r];
            int a1i = u1i[m][r];
            #pragma unroll
            for (int mask = 1; mask <= 8; mask <<= 1) {
                float b1 = __shfl_xor(a1, mask);
                int b1i = __shfl_xor(a1i, mask);
                float b2 = __shfl_xor(a2, mask);
                if (b1 > a1) { a2 = fmaxf(a1, b2); a1 = b1; a1i = b1i; }
                else         { a2 = fmaxf(b1, a2); }
            }
            if (c15 == 0) {
                const int rl = m * 16 + g * 4 + r;   // 0..31
                sv1[rl][q] = a1;
                si1[rl][q] = a1i;
                sv2[rl][q] = a2;
            }
        }
    __syncthreads();
    // ---- cross-quarter merge (ascending q = ascending cols; ties keep lower) --
    if (t < 32) {
        float U1 = sv1[t][0], Us = sv2[t][0];
        int I1 = si1[t][0];
        #pragma unroll
        for (int qq = 1; qq < 4; ++qq) {
            float a = sv1[t][qq], b2 = sv2[t][qq];
            int ai = si1[t][qq];
            if (a > U1) { Us = fmaxf(U1, b2); U1 = a; I1 = ai; }
            else        { Us = fmaxf(Us, a); }
        }
        cand[row0 + t] = I1;
        thr[row0 + t] = Us;
    }
}

// ---------------- resolve: exact fp32 score of candidate; safe iff > thr -----
__global__ __launch_bounds__(256) void resolve_kernel(
    const float* __restrict__ rep, const float* __restrict__ cb,
    const float* __restrict__ c2h, const int* __restrict__ cand,
    const float* __restrict__ thr, int* __restrict__ out,
    int* __restrict__ cnt, int* __restrict__ list, int N) {
    const int W = (blockIdx.x * 256 + threadIdx.x) >> 6;
    const int lane = threadIdx.x & 63;
    if (W >= N) return;
    const int ci = cand[W];
    const float4 rv = *(const float4*)(rep + (size_t)W * DIM + lane * 4);
    const float4 cv = *(const float4*)(cb + (size_t)ci * DIM + lane * 4);
    float p = rv.x * cv.x + rv.y * cv.y + rv.z * cv.z + rv.w * cv.w;
    #pragma unroll
    for (int off = 32; off > 0; off >>= 1) p += __shfl_down(p, off);
    if (lane == 0) {
        float sex = p - c2h[ci];
        out[W] = ci;                              // provisional
        if (!(sex > thr[W])) {                    // not provably optimal
            int pos = atomicAdd(cnt, 1);
            list[pos] = W;
        }
    }
}

// ---------------- rescan: (row-group x kt) parallel exact 4-pass tiles -------
__global__ __launch_bounds__(256) void rescan_kernel(
    const float* __restrict__ rep, const float* __restrict__ cb,
    const float* __restrict__ c2h, const int* __restrict__ cnt_p,
    const int* __restrict__ list, unsigned long long* __restrict__ keys) {

    const int cnt = *cnt_p;
    const int base = blockIdx.x * 64;
    if (base >= cnt) return;
    const int nrows = min(64, cnt - base);
    const int ktbase = (int)blockIdx.y * BN;

    __shared__ __align__(16) h16 lds[2][BN * 64];
    const int t = threadIdx.x;
    const int lane = t & 63;
    const int w = t >> 6;
    const int c15 = lane & 15;
    const int g = lane >> 4;
    const int wrow = w * 16;

    const int aslot = wrow + c15;
    const int grow = list[base + (aslot < nrows ? aslot : 0)];
    f16x8 ah[8], al[8];
    {
        const float* ar = rep + (size_t)grow * DIM + g * 8;
        #pragma unroll
        for (int ch = 0; ch < 8; ++ch) {
            float x[8];
            *(float4*)&x[0] = *(const float4*)(ar + ch * 32);
            *(float4*)&x[4] = *(const float4*)(ar + ch * 32 + 4);
            split8(x, ah[ch], al[ch]);
        }
    }
    f32x4 acc[8];
    float cc[8];
    #pragma unroll
    for (int n = 0; n < 8; ++n) {
        #pragma unroll
        for (int r = 0; r < 4; ++r) acc[n][r] = 0.f;
        cc[n] = c2h[ktbase + n * 16 + c15];
    }

    const int scol = t >> 1;
    const int dslot = t & 1;
    float breg[16];
    auto loadB = [&](int ch) {
        const float* src = cb + (size_t)(ktbase + scol) * DIM + ch * 32 + dslot * 16;
        #pragma unroll
        for (int i = 0; i < 4; ++i) *(float4*)&breg[i * 4] = *(const float4*)(src + i * 4);
    };
    auto writeB = [&](int buf) {
        #pragma unroll
        for (int half = 0; half < 2; ++half) {
            f16x8 hh, ll;
            split8(&breg[half * 8], hh, ll);
            const int s = dslot * 2 + half;
            *(f16x8*)&lds[buf][scol * 64 + ((s ^ (scol & 7)) << 3)] = hh;
            *(f16x8*)&lds[buf][scol * 64 + (((s + 4) ^ (scol & 7)) << 3)] = ll;
        }
    };

    loadB(0);
    writeB(0);
    loadB(1);
    __syncthreads();

    #pragma unroll
    for (int chunk = 0; chunk < 8; ++chunk) {
        const int buf = chunk & 1;
        if (chunk != 7) writeB(buf ^ 1);
        if (chunk <= 5) loadB(chunk + 2);
        #pragma unroll
        for (int n = 0; n < 8; ++n) {
            const int bb = (n * 16 + c15) * 64;
            f16x8 bh = *(const f16x8*)&lds[buf][bb + ((g ^ (lane & 7)) << 3)];
            f16x8 bl = *(const f16x8*)&lds[buf][bb + (((4 + g) ^ (lane & 7)) << 3)];
            acc[n] = __builtin_amdgcn_mfma_f32_16x16x32_f16(ah[chunk], bh, acc[n], 0, 0, 0);
            acc[n] = __builtin_amdgcn_mfma_f32_16x16x32_f16(ah[chunk], bl, acc[n], 0, 0, 0);
            acc[n] = __builtin_amdgcn_mfma_f32_16x16x32_f16(al[chunk], bh, acc[n], 0, 0, 0);
            acc[n] = __builtin_amdgcn_mfma_f32_16x16x32_f16(al[chunk], bl, acc[n], 0, 0, 0);
        }
        __syncthreads();
    }

    #pragma unroll
    for (int r = 0; r < 4; ++r) {
        float bv = -3.4e38f;
        int bi = 0;
        #pragma unroll
        for (int n = 0; n < 8; ++n) {
            float s2 = acc[n][r] - cc[n];
            const int col = ktbase + n * 16 + c15;
            if (s2 > bv) { bv = s2; bi = col; }
        }
        #pragma unroll
        for (int mask = 1; mask <= 8; mask <<= 1) {
            float ov = __shfl_xor(bv, mask);
            int oi = __shfl_xor(bi, mask);
            if (ov > bv || (ov == bv && oi < bi)) { bv = ov; bi = oi; }
        }
        const int oslot = wrow + g * 4 + r;
        if (c15 == 0 && oslot < nrows) {
            unsigned long long key =
                ((unsigned long long)ford(bv) << 32) | (unsigned int)(~(unsigned int)bi);
            atomicMax(&keys[list[base + oslot]], key);
        }
    }
}

// ---------------- writeback listed rows from merged keys ----------------
__global__ __launch_bounds__(256) void writeback_kernel(
    const int* __restrict__ cnt_p, const int* __restrict__ list,
    const unsigned long long* __restrict__ keys, int* __restrict__ out) {
    int i = blockIdx.x * 256 + threadIdx.x;
    if (i >= *cnt_p) return;
    int row = list[i];
    out[row] = (int)(~(unsigned int)(keys[row] & 0xFFFFFFFFull));
}

extern "C" void kernel_launch(void* const* d_in, const int* in_sizes, int n_in,
                              void* d_out, int out_size, void* d_ws, size_t ws_size,
                              hipStream_t stream) {
    const float* rep = (const float*)d_in[0];
    const float* cb = (const float*)d_in[1];
    const int N = in_sizes[0] / DIM;   // 65536
    const int K = in_sizes[1] / DIM;   // 8192
    char* ws = (char*)d_ws;
    float* c2h = (float*)(ws + WS_C2H);
    float* lc  = (float*)(ws + WS_LC);
    float* cn  = (float*)(ws + WS_CN);
    int* cnt   = (int*)(ws + WS_CNT);
    unsigned int* gmx = (unsigned int*)(ws + WS_CNT + 4);
    int* list  = (int*)(ws + WS_LIST);
    int* cand  = (int*)(ws + WS_CAND);
    float* thr = (float*)(ws + WS_THR);
    unsigned long long* keys = (unsigned long long*)(ws + WS_KEYS);
    h16* Bph   = (h16*)(ws + WS_BPH);
    int* out = (int*)d_out;

    hipMemsetAsync(ws + WS_CNT, 0, 64, stream);   // cnt + gmx
    hipMemsetAsync(keys, 0, (size_t)N * sizeof(unsigned long long), stream);
    c2x_kernel<<<dim3((K * 64 + 255) / 256), dim3(256), 0, stream>>>(cb, c2h, lc, cn, gmx, K);
    pack_h2_kernel<<<dim3(KCODES * 32 / 256), dim3(256), 0, stream>>>(cb, Bph);
    vq_pass1<<<dim3(N / 32), dim3(256), 0, stream>>>(rep, Bph, c2h, gmx, cand, thr);
    resolve_kernel<<<dim3(N / 4), dim3(256), 0, stream>>>(rep, cb, c2h, cand, thr, out, cnt, list, N);
    rescan_kernel<<<dim3(N / 64, NKT), dim3(256), 0, stream>>>(rep, cb, c2h, cnt, list, keys);
    writeback_kernel<<<dim3(N / 256), dim3(256), 0, stream>>>(cnt, list, keys, out);
}

// Round 16
// 989.740 us; speedup vs baseline: 1.0872x; 1.0872x over previous
//
#include <hip/hip_runtime.h>
#include <stdint.h>

#define KCODES 8192
#define DIM 256
#define BN 128              // codebook cols per kt tile
#define NKT (KCODES / BN)   // 64 tiles
#define NSTEP (NKT * 4)     // 256 steps of 64 d (one 16 KB pair-block each)

typedef _Float16 h16;
typedef __attribute__((ext_vector_type(8))) _Float16 f16x8;
typedef __attribute__((ext_vector_type(4))) float f32x4;

__device__ __forceinline__ void split8(const float* __restrict__ x, f16x8& h, f16x8& l) {
    #pragma unroll
    for (int i = 0; i < 8; ++i) {
        float v = x[i];
        _Float16 hv = (_Float16)v;          // RNE
        h[i] = hv;
        l[i] = (_Float16)(v - (float)hv);   // exact residual in f32, RNE to f16
    }
}

__device__ __forceinline__ unsigned int ford(float f) {   // monotone float->uint
    unsigned int b = __float_as_uint(f);
    return (b & 0x80000000u) ? ~b : (b | 0x80000000u);
}

// ---- ws layout (bytes); ws >= 8.4 MB (proven R5-R15) ----
#define WS_C2H   0u
#define WS_CNT   98304u      // int cnt; +4: u32 gmaxLC; +8: u32 gmaxCN
#define WS_LIST  98560u
#define WS_CAND  360704u
#define WS_THR   622848u
#define WS_KEYS  917504u
#define WS_BPH   2097152u    // 4 MB h-only packed image

// ---------------- fused prep: pack h-image + c2h + global maxima -------------
// Pack layout (proven R11-R13): 256 pair-blocks of 16 KB; pair P = kt*4 +
// (chunk>>1); logical slot s = (chunk&1)*4 + g holds h of d [chunk*32+g*8..+7]
// of code kt*128+col; phys = s ^ (col&7).
// Norms: the 32 threads of one code reduce via __shfl_xor (stay in 32-half).
__global__ __launch_bounds__(256) void prep_kernel(const float* __restrict__ cb,
                                                   h16* __restrict__ Bp,
                                                   float* __restrict__ c2h,
                                                   unsigned int* __restrict__ gmx) {
    const int tid = blockIdx.x * 256 + threadIdx.x;   // 8192*32
    const int code = tid >> 5;
    const int grp = tid & 31;                         // 8-d group
    float x[8];
    *(float4*)&x[0] = *(const float4*)(cb + (size_t)code * DIM + grp * 8);
    *(float4*)&x[4] = *(const float4*)(cb + (size_t)code * DIM + grp * 8 + 4);
    f16x8 hh;
    float s = 0.f, sr = 0.f;
    #pragma unroll
    for (int i = 0; i < 8; ++i) {
        float v = x[i];
        _Float16 hv = (_Float16)v;
        hh[i] = hv;
        s += v * v;
        float rho = v - (float)hv;
        sr += rho * rho;
    }
    const int kt = code >> 7, col = code & 127;
    const int chunk = grp >> 2, g = grp & 3;
    const int P = kt * 4 + (chunk >> 1);
    const int sl = (chunk & 1) * 4 + g;
    const int phys = sl ^ (col & 7);
    *(f16x8*)(Bp + (size_t)P * 8192 + col * 64 + phys * 8) = hh;

    #pragma unroll
    for (int off = 16; off > 0; off >>= 1) {
        s += __shfl_xor(s, off);
        sr += __shfl_xor(sr, off);
    }
    if (grp == 0) {
        c2h[code] = 0.5f * s;
        atomicMax(&gmx[0], __float_as_uint(sqrtf(sr)));   // max ||rho_c||
        atomicMax(&gmx[1], __float_as_uint(sqrtf(s)));    // max ||c||
    }
}

// ---------------- pass 1: hh scores + per-row top-2 of upper bound u ---------
// R13 body with ring-2 (32 KB LDS) -> 4-5 independent barrier groups/CU.
// Wave tile 32x64 (m2 x n4 of 16x16x32), A pre-split in regs. Per step:
// top-wait vmcnt(0) (staging had a full step in flight), barrier, issue s+1
// into other buffer, 8 ds_read + 16 MFMA. Row-only bound U[m][r] (R14-proven).
__global__ __launch_bounds__(256, 5) void vq_pass1(
    const float* __restrict__ rep, const h16* __restrict__ Bp,
    const float* __restrict__ c2h, const unsigned int* __restrict__ gmx,
    int* __restrict__ cand, float* __restrict__ thr) {

    __shared__ __align__(16) h16 buf[2][8192];   // 32 KB

    const int t = threadIdx.x;
    const int lane = t & 63;
    const int c15 = lane & 15;
    const int g = lane >> 4;
    const int w = t >> 6;                 // wave 0..3
    const int wrow = (w >> 1) * 32;       // row half 0/32
    const int wcol = (w & 1) * 64;        // col half 0/64
    const int row0 = blockIdx.x * 64;

    const float Lmax = __uint_as_float(gmx[0]);
    const float Cmax = __uint_as_float(gmx[1]);

    // ---- A: h fragments + row-correct bound U[m][r] ----
    f16x8 ah[2][8];
    float U[2][4];
    #pragma unroll
    for (int m = 0; m < 2; ++m) {
        const float* ar = rep + (size_t)(row0 + wrow + m * 16 + c15) * DIM + g * 8;
        float hs = 0.f, rs = 0.f;
        #pragma unroll
        for (int ch = 0; ch < 8; ++ch) {
            float x[8];
            *(float4*)&x[0] = *(const float4*)(ar + ch * 32);
            *(float4*)&x[4] = *(const float4*)(ar + ch * 32 + 4);
            #pragma unroll
            for (int i = 0; i < 8; ++i) {
                _Float16 hv = (_Float16)x[i];
                ah[m][ch][i] = hv;
                float hf = (float)hv;
                hs += hf * hf;
                float rho = x[i] - hf;
                rs += rho * rho;
            }
        }
        hs += __shfl_xor(hs, 16); hs += __shfl_xor(hs, 32);
        rs += __shfl_xor(rs, 16); rs += __shfl_xor(rs, 32);
        float hn = sqrtf(hs), rn = sqrtf(rs);
        // C/D rows for this lane are g*4+r -> fetch those rows' norms
        #pragma unroll
        for (int r = 0; r < 4; ++r) {
            float hnr = __shfl(hn, g * 4 + r);
            float rnr = __shfl(rn, g * 4 + r);
            U[m][r] = fmaf(hnr, Lmax, fmaf(rnr, Cmax, 0.012f));
        }
    }

    f32x4 acc[2][4];
    float u1v[2][4], u2v[2][4], D[4];
    int u1i[2][4];
    #pragma unroll
    for (int m = 0; m < 2; ++m)
        #pragma unroll
        for (int r = 0; r < 4; ++r) { u1v[m][r] = -3.4e38f; u2v[m][r] = -3.4e38f; u1i[m][r] = 0; }

    auto issueStep = [&](int s2, int b) {   // stage one 16 KB pair-block
        const h16* src = Bp + (size_t)s2 * 8192 + t * 8;
        h16* dst = &buf[b][t * 8];
        #pragma unroll
        for (int i = 0; i < 4; ++i)
            __builtin_amdgcn_global_load_lds(
                (const __attribute__((address_space(1))) uint32_t*)(src + i * 2048),
                (__attribute__((address_space(3))) uint32_t*)(dst + i * 2048),
                16, 0, 0);
    };

    issueStep(0, 0);

    #pragma unroll 1
    for (int kt = 0; kt < NKT; ++kt) {
        const int ktbase = kt * BN;
        #pragma unroll
        for (int cp = 0; cp < 4; ++cp) {            // step s = kt*4+cp; 64 d
            const int s = kt * 4 + cp;
            const int par = cp & 1;                 // == s & 1, compile-time
            // s's staging (issued one full step ago) + older D loads drain.
            asm volatile("s_waitcnt vmcnt(0) lgkmcnt(0)" ::: "memory");
            __builtin_amdgcn_s_barrier();
            __builtin_amdgcn_sched_barrier(0);

            if (cp == 0) {
                #pragma unroll
                for (int n = 0; n < 4; ++n) D[n] = c2h[ktbase + wcol + n * 16 + c15];
                #pragma unroll
                for (int m = 0; m < 2; ++m)
                    #pragma unroll
                    for (int n = 0; n < 4; ++n)
                        #pragma unroll
                        for (int r = 0; r < 4; ++r) acc[m][n][r] = U[m][r];
            }
            if (s + 1 < NSTEP) issueStep(s + 1, par ^ 1);

            const h16* lb = &buf[par][0];
            #pragma unroll
            for (int j = 0; j < 2; ++j) {
                const int ch = cp * 2 + j;          // compile-time d-chunk 0..7
                #pragma unroll
                for (int n = 0; n < 4; ++n) {
                    const int base = (wcol + n * 16 + c15) * 64;
                    f16x8 bh = *(const f16x8*)&lb[base + (((j * 4 + g) ^ (c15 & 7)) << 3)];
                    #pragma unroll
                    for (int m = 0; m < 2; ++m)
                        acc[m][n] = __builtin_amdgcn_mfma_f32_16x16x32_f16(ah[m][ch], bh, acc[m][n], 0, 0, 0);
                }
            }

            if (cp == 3) {   // per-kt epilogue: u = acc - cc; track top-2
                #pragma unroll
                for (int n = 0; n < 4; ++n) {
                    const int col = ktbase + wcol + n * 16 + c15;
                    #pragma unroll
                    for (int m = 0; m < 2; ++m)
                        #pragma unroll
                        for (int r = 0; r < 4; ++r) {
                            float u = acc[m][n][r] - D[n];
                            if (u > u1v[m][r]) { u2v[m][r] = u1v[m][r]; u1v[m][r] = u; u1i[m][r] = col; }
                            else if (u > u2v[m][r]) u2v[m][r] = u;
                        }
                }
            }
        }
    }

    // ---- merge top-2 across 16 c15-lanes, then across col-half waves ----
    __syncthreads();   // all compute done; buf[0] becomes scratch
    float* sv1 = (float*)&buf[0][0];           // [row 0..63][half 0..1]
    int* si1 = (int*)((char*)&buf[0][0] + 1024);
    float* sv2 = (float*)((char*)&buf[0][0] + 2048);
    #pragma unroll
    for (int m = 0; m < 2; ++m)
        #pragma unroll
        for (int r = 0; r < 4; ++r) {
            float a1 = u1v[m][r], a2 = u2v[m][r];
            int a1i = u1i[m][r];
            #pragma unroll
            for (int mask = 1; mask <= 8; mask <<= 1) {
                float b1 = __shfl_xor(a1, mask);
                int b1i = __shfl_xor(a1i, mask);
                float b2 = __shfl_xor(a2, mask);
                if (b1 > a1) { a2 = fmaxf(a1, b2); a1 = b1; a1i = b1i; }
                else         { a2 = fmaxf(b1, a2); }
            }
            if (c15 == 0) {
                const int rl = wrow + m * 16 + g * 4 + r;   // 0..63
                sv1[rl * 2 + (w & 1)] = a1;
                si1[rl * 2 + (w & 1)] = a1i;
                sv2[rl * 2 + (w & 1)] = a2;
            }
        }
    __syncthreads();
    if (t < 64) {
        float a1 = sv1[t * 2], a2 = sv2[t * 2];
        int a1i = si1[t * 2];
        float b1 = sv1[t * 2 + 1], b2 = sv2[t * 2 + 1];
        int b1i = si1[t * 2 + 1];
        float u1, u2; int u1idx;
        if (b1 > a1) { u1 = b1; u1idx = b1i; u2 = fmaxf(a1, b2); }
        else         { u1 = a1; u1idx = a1i; u2 = fmaxf(b1, a2); }
        cand[row0 + t] = u1idx;
        thr[row0 + t] = u2;
    }
}

// ---------------- resolve: exact fp32 score of candidate; safe iff > thr -----
__global__ __launch_bounds__(256) void resolve_kernel(
    const float* __restrict__ rep, const float* __restrict__ cb,
    const float* __restrict__ c2h, const int* __restrict__ cand,
    const float* __restrict__ thr, int* __restrict__ out,
    int* __restrict__ cnt, int* __restrict__ list, int N) {
    const int W = (blockIdx.x * 256 + threadIdx.x) >> 6;
    const int lane = threadIdx.x & 63;
    if (W >= N) return;
    const int ci = cand[W];
    const float4 rv = *(const float4*)(rep + (size_t)W * DIM + lane * 4);
    const float4 cv = *(const float4*)(cb + (size_t)ci * DIM + lane * 4);
    float p = rv.x * cv.x + rv.y * cv.y + rv.z * cv.z + rv.w * cv.w;
    #pragma unroll
    for (int off = 32; off > 0; off >>= 1) p += __shfl_down(p, off);
    if (lane == 0) {
        float sex = p - c2h[ci];
        out[W] = ci;                              // provisional
        if (!(sex > thr[W])) {                    // not provably optimal
            int pos = atomicAdd(cnt, 1);
            list[pos] = W;
        }
    }
}

// ---------------- rescan: (row-group x kt) parallel exact 4-pass tiles -------
__global__ __launch_bounds__(256) void rescan_kernel(
    const float* __restrict__ rep, const float* __restrict__ cb,
    const float* __restrict__ c2h, const int* __restrict__ cnt_p,
    const int* __restrict__ list, unsigned long long* __restrict__ keys) {

    const int cnt = *cnt_p;
    const int base = blockIdx.x * 64;
    if (base >= cnt) return;
    const int nrows = min(64, cnt - base);
    const int ktbase = (int)blockIdx.y * BN;

    __shared__ __align__(16) h16 lds[2][BN * 64];
    const int t = threadIdx.x;
    const int lane = t & 63;
    const int w = t >> 6;
    const int c15 = lane & 15;
    const int g = lane >> 4;
    const int wrow = w * 16;

    const int aslot = wrow + c15;
    const int grow = list[base + (aslot < nrows ? aslot : 0)];
    f16x8 ah[8], al[8];
    {
        const float* ar = rep + (size_t)grow * DIM + g * 8;
        #pragma unroll
        for (int ch = 0; ch < 8; ++ch) {
            float x[8];
            *(float4*)&x[0] = *(const float4*)(ar + ch * 32);
            *(float4*)&x[4] = *(const float4*)(ar + ch * 32 + 4);
            split8(x, ah[ch], al[ch]);
        }
    }
    f32x4 acc[8];
    float cc[8];
    #pragma unroll
    for (int n = 0; n < 8; ++n) {
        #pragma unroll
        for (int r = 0; r < 4; ++r) acc[n][r] = 0.f;
        cc[n] = c2h[ktbase + n * 16 + c15];
    }

    const int scol = t >> 1;
    const int dslot = t & 1;
    float breg[16];
    auto loadB = [&](int ch) {
        const float* src = cb + (size_t)(ktbase + scol) * DIM + ch * 32 + dslot * 16;
        #pragma unroll
        for (int i = 0; i < 4; ++i) *(float4*)&breg[i * 4] = *(const float4*)(src + i * 4);
    };
    auto writeB = [&](int buf) {
        #pragma unroll
        for (int half = 0; half < 2; ++half) {
            f16x8 hh, ll;
            split8(&breg[half * 8], hh, ll);
            const int s = dslot * 2 + half;
            *(f16x8*)&lds[buf][scol * 64 + ((s ^ (scol & 7)) << 3)] = hh;
            *(f16x8*)&lds[buf][scol * 64 + (((s + 4) ^ (scol & 7)) << 3)] = ll;
        }
    };

    loadB(0);
    writeB(0);
    loadB(1);
    __syncthreads();

    #pragma unroll
    for (int chunk = 0; chunk < 8; ++chunk) {
        const int buf = chunk & 1;
        if (chunk != 7) writeB(buf ^ 1);
        if (chunk <= 5) loadB(chunk + 2);
        #pragma unroll
        for (int n = 0; n < 8; ++n) {
            const int bb = (n * 16 + c15) * 64;
            f16x8 bh = *(const f16x8*)&lds[buf][bb + ((g ^ (lane & 7)) << 3)];
            f16x8 bl = *(const f16x8*)&lds[buf][bb + (((4 + g) ^ (lane & 7)) << 3)];
            acc[n] = __builtin_amdgcn_mfma_f32_16x16x32_f16(ah[chunk], bh, acc[n], 0, 0, 0);
            acc[n] = __builtin_amdgcn_mfma_f32_16x16x32_f16(ah[chunk], bl, acc[n], 0, 0, 0);
            acc[n] = __builtin_amdgcn_mfma_f32_16x16x32_f16(al[chunk], bh, acc[n], 0, 0, 0);
            acc[n] = __builtin_amdgcn_mfma_f32_16x16x32_f16(al[chunk], bl, acc[n], 0, 0, 0);
        }
        __syncthreads();
    }

    #pragma unroll
    for (int r = 0; r < 4; ++r) {
        float bv = -3.4e38f;
        int bi = 0;
        #pragma unroll
        for (int n = 0; n < 8; ++n) {
            float s2 = acc[n][r] - cc[n];
            const int col = ktbase + n * 16 + c15;
            if (s2 > bv) { bv = s2; bi = col; }
        }
        #pragma unroll
        for (int mask = 1; mask <= 8; mask <<= 1) {
            float ov = __shfl_xor(bv, mask);
            int oi = __shfl_xor(bi, mask);
            if (ov > bv || (ov == bv && oi < bi)) { bv = ov; bi = oi; }
        }
        const int oslot = wrow + g * 4 + r;
        if (c15 == 0 && oslot < nrows) {
            unsigned long long key =
                ((unsigned long long)ford(bv) << 32) | (unsigned int)(~(unsigned int)bi);
            atomicMax(&keys[list[base + oslot]], key);
        }
    }
}

// ---------------- writeback listed rows from merged keys ----------------
__global__ __launch_bounds__(256) void writeback_kernel(
    const int* __restrict__ cnt_p, const int* __restrict__ list,
    const unsigned long long* __restrict__ keys, int* __restrict__ out) {
    int i = blockIdx.x * 256 + threadIdx.x;
    if (i >= *cnt_p) return;
    int row = list[i];
    out[row] = (int)(~(unsigned int)(keys[row] & 0xFFFFFFFFull));
}

extern "C" void kernel_launch(void* const* d_in, const int* in_sizes, int n_in,
                              void* d_out, int out_size, void* d_ws, size_t ws_size,
                              hipStream_t stream) {
    const float* rep = (const float*)d_in[0];
    const float* cb = (const float*)d_in[1];
    const int N = in_sizes[0] / DIM;   // 65536
    const int K = in_sizes[1] / DIM;   // 8192
    (void)K;
    char* ws = (char*)d_ws;
    float* c2h = (float*)(ws + WS_C2H);
    int* cnt   = (int*)(ws + WS_CNT);
    unsigned int* gmx = (unsigned int*)(ws + WS_CNT + 4);
    int* list  = (int*)(ws + WS_LIST);
    int* cand  = (int*)(ws + WS_CAND);
    float* thr = (float*)(ws + WS_THR);
    unsigned long long* keys = (unsigned long long*)(ws + WS_KEYS);
    h16* Bph   = (h16*)(ws + WS_BPH);
    int* out = (int*)d_out;

    hipMemsetAsync(ws + WS_CNT, 0, 64, stream);   // cnt + gmx
    hipMemsetAsync(keys, 0, (size_t)N * sizeof(unsigned long long), stream);
    prep_kernel<<<dim3(KCODES * 32 / 256), dim3(256), 0, stream>>>(cb, Bph, c2h, gmx);
    vq_pass1<<<dim3(N / 64), dim3(256), 0, stream>>>(rep, Bph, c2h, gmx, cand, thr);
    resolve_kernel<<<dim3(N / 4), dim3(256), 0, stream>>>(rep, cb, c2h, cand, thr, out, cnt, list, N);
    rescan_kernel<<<dim3(N / 64, NKT), dim3(256), 0, stream>>>(rep, cb, c2h, cnt, list, keys);
    writeback_kernel<<<dim3(N / 256), dim3(256), 0, stream>>>(cnt, list, keys, out);
}

// Round 17
// 677.875 us; speedup vs baseline: 1.5873x; 1.4601x over previous
//
#include <hip/hip_runtime.h>
#include <stdint.h>

#define KCODES 8192
#define DIM 256
#define BN 128              // codebook cols per kt tile
#define NKT (KCODES / BN)   // 64 tiles
#define NSTEP (NKT * 4)     // 256 steps of 64 d (one 16 KB pair-block each)

typedef _Float16 h16;
typedef __attribute__((ext_vector_type(8))) _Float16 f16x8;
typedef __attribute__((ext_vector_type(4))) float f32x4;

__device__ __forceinline__ void split8(const float* __restrict__ x, f16x8& h, f16x8& l) {
    #pragma unroll
    for (int i = 0; i < 8; ++i) {
        float v = x[i];
        _Float16 hv = (_Float16)v;          // RNE
        h[i] = hv;
        l[i] = (_Float16)(v - (float)hv);   // exact residual in f32, RNE to f16
    }
}

__device__ __forceinline__ unsigned int ford(float f) {   // monotone float->uint
    unsigned int b = __float_as_uint(f);
    return (b & 0x80000000u) ? ~b : (b | 0x80000000u);
}

// ---- ws layout (bytes); ws >= 8.4 MB (proven R5-R16) ----
#define WS_C2H   0u
#define WS_CNT   98304u      // int cnt; +4: u32 gmaxLC; +8: u32 gmaxCN
#define WS_LIST  98560u
#define WS_CAND  360704u
#define WS_THR   622848u
#define WS_KEYS  917504u
#define WS_BPH   2097152u    // 4 MB h-only packed image

// ---------------- fused prep: pack h-image + c2h + global maxima -------------
// Pack layout (proven R11-R16): 256 pair-blocks of 16 KB; pair P = kt*4 +
// (chunk>>1); logical slot s = (chunk&1)*4 + g holds h of d [chunk*32+g*8..+7]
// of code kt*128+col; phys = s ^ (col&7).
__global__ __launch_bounds__(256) void prep_kernel(const float* __restrict__ cb,
                                                   h16* __restrict__ Bp,
                                                   float* __restrict__ c2h,
                                                   unsigned int* __restrict__ gmx) {
    const int tid = blockIdx.x * 256 + threadIdx.x;   // 8192*32
    const int code = tid >> 5;
    const int grp = tid & 31;                         // 8-d group
    float x[8];
    *(float4*)&x[0] = *(const float4*)(cb + (size_t)code * DIM + grp * 8);
    *(float4*)&x[4] = *(const float4*)(cb + (size_t)code * DIM + grp * 8 + 4);
    f16x8 hh;
    float s = 0.f, sr = 0.f;
    #pragma unroll
    for (int i = 0; i < 8; ++i) {
        float v = x[i];
        _Float16 hv = (_Float16)v;
        hh[i] = hv;
        s += v * v;
        float rho = v - (float)hv;
        sr += rho * rho;
    }
    const int kt = code >> 7, col = code & 127;
    const int chunk = grp >> 2, g = grp & 3;
    const int P = kt * 4 + (chunk >> 1);
    const int sl = (chunk & 1) * 4 + g;
    const int phys = sl ^ (col & 7);
    *(f16x8*)(Bp + (size_t)P * 8192 + col * 64 + phys * 8) = hh;

    #pragma unroll
    for (int off = 16; off > 0; off >>= 1) {
        s += __shfl_xor(s, off);
        sr += __shfl_xor(sr, off);
    }
    if (grp == 0) {
        c2h[code] = 0.5f * s;
        atomicMax(&gmx[0], __float_as_uint(sqrtf(sr)));   // max ||rho_c||
        atomicMax(&gmx[1], __float_as_uint(sqrtf(s)));    // max ||c||
    }
}

// ---------------- pass 1: hh scores + per-row top-2 of upper bound u ---------
// Ring-2 (32 KB LDS), NO launch_bounds occupancy arg: compiler allocates
// ~84 VGPR freely (R13-measured body) -> occupancy LDS-bound at 5 blocks/CU
// = 5 independent barrier groups (R16's (256,5) capped VGPR at 48 -> spill).
// Wave tile 32x64 (m2 x n4 of 16x16x32), A pre-split in regs. Per step:
// top-wait vmcnt(0) (staging had a full step in flight), barrier, issue s+1
// into other buffer, 8 ds_read + 16 MFMA. Row-only bound U[m][r].
__global__ __launch_bounds__(256) void vq_pass1(
    const float* __restrict__ rep, const h16* __restrict__ Bp,
    const float* __restrict__ c2h, const unsigned int* __restrict__ gmx,
    int* __restrict__ cand, float* __restrict__ thr) {

    __shared__ __align__(16) h16 buf[2][8192];   // 32 KB

    const int t = threadIdx.x;
    const int lane = t & 63;
    const int c15 = lane & 15;
    const int g = lane >> 4;
    const int w = t >> 6;                 // wave 0..3
    const int wrow = (w >> 1) * 32;       // row half 0/32
    const int wcol = (w & 1) * 64;        // col half 0/64
    const int row0 = blockIdx.x * 64;

    const float Lmax = __uint_as_float(gmx[0]);
    const float Cmax = __uint_as_float(gmx[1]);

    // ---- A: h fragments + row-correct bound U[m][r] ----
    f16x8 ah[2][8];
    float U[2][4];
    #pragma unroll
    for (int m = 0; m < 2; ++m) {
        const float* ar = rep + (size_t)(row0 + wrow + m * 16 + c15) * DIM + g * 8;
        float hs = 0.f, rs = 0.f;
        #pragma unroll
        for (int ch = 0; ch < 8; ++ch) {
            float x[8];
            *(float4*)&x[0] = *(const float4*)(ar + ch * 32);
            *(float4*)&x[4] = *(const float4*)(ar + ch * 32 + 4);
            #pragma unroll
            for (int i = 0; i < 8; ++i) {
                _Float16 hv = (_Float16)x[i];
                ah[m][ch][i] = hv;
                float hf = (float)hv;
                hs += hf * hf;
                float rho = x[i] - hf;
                rs += rho * rho;
            }
        }
        hs += __shfl_xor(hs, 16); hs += __shfl_xor(hs, 32);
        rs += __shfl_xor(rs, 16); rs += __shfl_xor(rs, 32);
        float hn = sqrtf(hs), rn = sqrtf(rs);
        // C/D rows for this lane are g*4+r -> fetch those rows' norms
        #pragma unroll
        for (int r = 0; r < 4; ++r) {
            float hnr = __shfl(hn, g * 4 + r);
            float rnr = __shfl(rn, g * 4 + r);
            U[m][r] = fmaf(hnr, Lmax, fmaf(rnr, Cmax, 0.012f));
        }
    }

    f32x4 acc[2][4];
    float u1v[2][4], u2v[2][4], D[4];
    int u1i[2][4];
    #pragma unroll
    for (int m = 0; m < 2; ++m)
        #pragma unroll
        for (int r = 0; r < 4; ++r) { u1v[m][r] = -3.4e38f; u2v[m][r] = -3.4e38f; u1i[m][r] = 0; }

    auto issueStep = [&](int s2, int b) {   // stage one 16 KB pair-block
        const h16* src = Bp + (size_t)s2 * 8192 + t * 8;
        h16* dst = &buf[b][t * 8];
        #pragma unroll
        for (int i = 0; i < 4; ++i)
            __builtin_amdgcn_global_load_lds(
                (const __attribute__((address_space(1))) uint32_t*)(src + i * 2048),
                (__attribute__((address_space(3))) uint32_t*)(dst + i * 2048),
                16, 0, 0);
    };

    issueStep(0, 0);

    #pragma unroll 1
    for (int kt = 0; kt < NKT; ++kt) {
        const int ktbase = kt * BN;
        #pragma unroll
        for (int cp = 0; cp < 4; ++cp) {            // step s = kt*4+cp; 64 d
            const int s = kt * 4 + cp;
            const int par = cp & 1;                 // == s & 1, compile-time
            // s's staging (issued one full step ago) + older D loads drain.
            asm volatile("s_waitcnt vmcnt(0) lgkmcnt(0)" ::: "memory");
            __builtin_amdgcn_s_barrier();
            __builtin_amdgcn_sched_barrier(0);

            if (cp == 0) {
                #pragma unroll
                for (int n = 0; n < 4; ++n) D[n] = c2h[ktbase + wcol + n * 16 + c15];
                #pragma unroll
                for (int m = 0; m < 2; ++m)
                    #pragma unroll
                    for (int n = 0; n < 4; ++n)
                        #pragma unroll
                        for (int r = 0; r < 4; ++r) acc[m][n][r] = U[m][r];
            }
            if (s + 1 < NSTEP) issueStep(s + 1, par ^ 1);

            const h16* lb = &buf[par][0];
            #pragma unroll
            for (int j = 0; j < 2; ++j) {
                const int ch = cp * 2 + j;          // compile-time d-chunk 0..7
                #pragma unroll
                for (int n = 0; n < 4; ++n) {
                    const int base = (wcol + n * 16 + c15) * 64;
                    f16x8 bh = *(const f16x8*)&lb[base + (((j * 4 + g) ^ (c15 & 7)) << 3)];
                    #pragma unroll
                    for (int m = 0; m < 2; ++m)
                        acc[m][n] = __builtin_amdgcn_mfma_f32_16x16x32_f16(ah[m][ch], bh, acc[m][n], 0, 0, 0);
                }
            }

            if (cp == 3) {   // per-kt epilogue: u = acc - cc; track top-2
                #pragma unroll
                for (int n = 0; n < 4; ++n) {
                    const int col = ktbase + wcol + n * 16 + c15;
                    #pragma unroll
                    for (int m = 0; m < 2; ++m)
                        #pragma unroll
                        for (int r = 0; r < 4; ++r) {
                            float u = acc[m][n][r] - D[n];
                            if (u > u1v[m][r]) { u2v[m][r] = u1v[m][r]; u1v[m][r] = u; u1i[m][r] = col; }
                            else if (u > u2v[m][r]) u2v[m][r] = u;
                        }
                }
            }
        }
    }

    // ---- merge top-2 across 16 c15-lanes, then across col-half waves ----
    __syncthreads();   // all compute done; buf[0] becomes scratch
    float* sv1 = (float*)&buf[0][0];           // [row 0..63][half 0..1]
    int* si1 = (int*)((char*)&buf[0][0] + 1024);
    float* sv2 = (float*)((char*)&buf[0][0] + 2048);
    #pragma unroll
    for (int m = 0; m < 2; ++m)
        #pragma unroll
        for (int r = 0; r < 4; ++r) {
            float a1 = u1v[m][r], a2 = u2v[m][r];
            int a1i = u1i[m][r];
            #pragma unroll
            for (int mask = 1; mask <= 8; mask <<= 1) {
                float b1 = __shfl_xor(a1, mask);
                int b1i = __shfl_xor(a1i, mask);
                float b2 = __shfl_xor(a2, mask);
                if (b1 > a1) { a2 = fmaxf(a1, b2); a1 = b1; a1i = b1i; }
                else         { a2 = fmaxf(b1, a2); }
            }
            if (c15 == 0) {
                const int rl = wrow + m * 16 + g * 4 + r;   // 0..63
                sv1[rl * 2 + (w & 1)] = a1;
                si1[rl * 2 + (w & 1)] = a1i;
                sv2[rl * 2 + (w & 1)] = a2;
            }
        }
    __syncthreads();
    if (t < 64) {
        float a1 = sv1[t * 2], a2 = sv2[t * 2];
        int a1i = si1[t * 2];
        float b1 = sv1[t * 2 + 1], b2 = sv2[t * 2 + 1];
        int b1i = si1[t * 2 + 1];
        float u1, u2; int u1idx;
        if (b1 > a1) { u1 = b1; u1idx = b1i; u2 = fmaxf(a1, b2); }
        else         { u1 = a1; u1idx = a1i; u2 = fmaxf(b1, a2); }
        cand[row0 + t] = u1idx;
        thr[row0 + t] = u2;
    }
}

// ---------------- resolve: exact fp32 score of candidate; safe iff > thr -----
__global__ __launch_bounds__(256) void resolve_kernel(
    const float* __restrict__ rep, const float* __restrict__ cb,
    const float* __restrict__ c2h, const int* __restrict__ cand,
    const float* __restrict__ thr, int* __restrict__ out,
    int* __restrict__ cnt, int* __restrict__ list, int N) {
    const int W = (blockIdx.x * 256 + threadIdx.x) >> 6;
    const int lane = threadIdx.x & 63;
    if (W >= N) return;
    const int ci = cand[W];
    const float4 rv = *(const float4*)(rep + (size_t)W * DIM + lane * 4);
    const float4 cv = *(const float4*)(cb + (size_t)ci * DIM + lane * 4);
    float p = rv.x * cv.x + rv.y * cv.y + rv.z * cv.z + rv.w * cv.w;
    #pragma unroll
    for (int off = 32; off > 0; off >>= 1) p += __shfl_down(p, off);
    if (lane == 0) {
        float sex = p - c2h[ci];
        out[W] = ci;                              // provisional
        if (!(sex > thr[W])) {                    // not provably optimal
            int pos = atomicAdd(cnt, 1);
            list[pos] = W;
        }
    }
}

// ---------------- rescan: (row-group x kt) parallel exact 4-pass tiles -------
__global__ __launch_bounds__(256) void rescan_kernel(
    const float* __restrict__ rep, const float* __restrict__ cb,
    const float* __restrict__ c2h, const int* __restrict__ cnt_p,
    const int* __restrict__ list, unsigned long long* __restrict__ keys) {

    const int cnt = *cnt_p;
    const int base = blockIdx.x * 64;
    if (base >= cnt) return;
    const int nrows = min(64, cnt - base);
    const int ktbase = (int)blockIdx.y * BN;

    __shared__ __align__(16) h16 lds[2][BN * 64];
    const int t = threadIdx.x;
    const int lane = t & 63;
    const int w = t >> 6;
    const int c15 = lane & 15;
    const int g = lane >> 4;
    const int wrow = w * 16;

    const int aslot = wrow + c15;
    const int grow = list[base + (aslot < nrows ? aslot : 0)];
    f16x8 ah[8], al[8];
    {
        const float* ar = rep + (size_t)grow * DIM + g * 8;
        #pragma unroll
        for (int ch = 0; ch < 8; ++ch) {
            float x[8];
            *(float4*)&x[0] = *(const float4*)(ar + ch * 32);
            *(float4*)&x[4] = *(const float4*)(ar + ch * 32 + 4);
            split8(x, ah[ch], al[ch]);
        }
    }
    f32x4 acc[8];
    float cc[8];
    #pragma unroll
    for (int n = 0; n < 8; ++n) {
        #pragma unroll
        for (int r = 0; r < 4; ++r) acc[n][r] = 0.f;
        cc[n] = c2h[ktbase + n * 16 + c15];
    }

    const int scol = t >> 1;
    const int dslot = t & 1;
    float breg[16];
    auto loadB = [&](int ch) {
        const float* src = cb + (size_t)(ktbase + scol) * DIM + ch * 32 + dslot * 16;
        #pragma unroll
        for (int i = 0; i < 4; ++i) *(float4*)&breg[i * 4] = *(const float4*)(src + i * 4);
    };
    auto writeB = [&](int buf) {
        #pragma unroll
        for (int half = 0; half < 2; ++half) {
            f16x8 hh, ll;
            split8(&breg[half * 8], hh, ll);
            const int s = dslot * 2 + half;
            *(f16x8*)&lds[buf][scol * 64 + ((s ^ (scol & 7)) << 3)] = hh;
            *(f16x8*)&lds[buf][scol * 64 + (((s + 4) ^ (scol & 7)) << 3)] = ll;
        }
    };

    loadB(0);
    writeB(0);
    loadB(1);
    __syncthreads();

    #pragma unroll
    for (int chunk = 0; chunk < 8; ++chunk) {
        const int buf = chunk & 1;
        if (chunk != 7) writeB(buf ^ 1);
        if (chunk <= 5) loadB(chunk + 2);
        #pragma unroll
        for (int n = 0; n < 8; ++n) {
            const int bb = (n * 16 + c15) * 64;
            f16x8 bh = *(const f16x8*)&lds[buf][bb + ((g ^ (lane & 7)) << 3)];
            f16x8 bl = *(const f16x8*)&lds[buf][bb + (((4 + g) ^ (lane & 7)) << 3)];
            acc[n] = __builtin_amdgcn_mfma_f32_16x16x32_f16(ah[chunk], bh, acc[n], 0, 0, 0);
            acc[n] = __builtin_amdgcn_mfma_f32_16x16x32_f16(ah[chunk], bl, acc[n], 0, 0, 0);
            acc[n] = __builtin_amdgcn_mfma_f32_16x16x32_f16(al[chunk], bh, acc[n], 0, 0, 0);
            acc[n] = __builtin_amdgcn_mfma_f32_16x16x32_f16(al[chunk], bl, acc[n], 0, 0, 0);
        }
        __syncthreads();
    }

    #pragma unroll
    for (int r = 0; r < 4; ++r) {
        float bv = -3.4e38f;
        int bi = 0;
        #pragma unroll
        for (int n = 0; n < 8; ++n) {
            float s2 = acc[n][r] - cc[n];
            const int col = ktbase + n * 16 + c15;
            if (s2 > bv) { bv = s2; bi = col; }
        }
        #pragma unroll
        for (int mask = 1; mask <= 8; mask <<= 1) {
            float ov = __shfl_xor(bv, mask);
            int oi = __shfl_xor(bi, mask);
            if (ov > bv || (ov == bv && oi < bi)) { bv = ov; bi = oi; }
        }
        const int oslot = wrow + g * 4 + r;
        if (c15 == 0 && oslot < nrows) {
            unsigned long long key =
                ((unsigned long long)ford(bv) << 32) | (unsigned int)(~(unsigned int)bi);
            atomicMax(&keys[list[base + oslot]], key);
        }
    }
}

// ---------------- writeback listed rows from merged keys ----------------
__global__ __launch_bounds__(256) void writeback_kernel(
    const int* __restrict__ cnt_p, const int* __restrict__ list,
    const unsigned long long* __restrict__ keys, int* __restrict__ out) {
    int i = blockIdx.x * 256 + threadIdx.x;
    if (i >= *cnt_p) return;
    int row = list[i];
    out[row] = (int)(~(unsigned int)(keys[row] & 0xFFFFFFFFull));
}

extern "C" void kernel_launch(void* const* d_in, const int* in_sizes, int n_in,
                              void* d_out, int out_size, void* d_ws, size_t ws_size,
                              hipStream_t stream) {
    const float* rep = (const float*)d_in[0];
    const float* cb = (const float*)d_in[1];
    const int N = in_sizes[0] / DIM;   // 65536
    const int K = in_sizes[1] / DIM;   // 8192
    (void)K;
    char* ws = (char*)d_ws;
    float* c2h = (float*)(ws + WS_C2H);
    int* cnt   = (int*)(ws + WS_CNT);
    unsigned int* gmx = (unsigned int*)(ws + WS_CNT + 4);
    int* list  = (int*)(ws + WS_LIST);
    int* cand  = (int*)(ws + WS_CAND);
    float* thr = (float*)(ws + WS_THR);
    unsigned long long* keys = (unsigned long long*)(ws + WS_KEYS);
    h16* Bph   = (h16*)(ws + WS_BPH);
    int* out = (int*)d_out;

    hipMemsetAsync(ws + WS_CNT, 0, 64, stream);   // cnt + gmx
    hipMemsetAsync(keys, 0, (size_t)N * sizeof(unsigned long long), stream);
    prep_kernel<<<dim3(KCODES * 32 / 256), dim3(256), 0, stream>>>(cb, Bph, c2h, gmx);
    vq_pass1<<<dim3(N / 64), dim3(256), 0, stream>>>(rep, Bph, c2h, gmx, cand, thr);
    resolve_kernel<<<dim3(N / 4), dim3(256), 0, stream>>>(rep, cb, c2h, cand, thr, out, cnt, list, N);
    rescan_kernel<<<dim3(N / 64, NKT), dim3(256), 0, stream>>>(rep, cb, c2h, cnt, list, keys);
    writeback_kernel<<<dim3(N / 256), dim3(256), 0, stream>>>(cnt, list, keys, out);
}

// Round 18
// 522.929 us; speedup vs baseline: 2.0577x; 1.2963x over previous
//
#include <hip/hip_runtime.h>
#include <stdint.h>

#define KCODES 8192
#define DIM 256
#define BN 128              // rescan col tile
#define NKT (KCODES / BN)   // 64 tiles
#define NSTEP (NKT * 4)     // 256 steps of 64 d

typedef _Float16 h16;
typedef __attribute__((ext_vector_type(8))) _Float16 f16x8;
typedef __attribute__((ext_vector_type(4))) float f32x4;

__device__ __forceinline__ void split8(const float* __restrict__ x, f16x8& h, f16x8& l) {
    #pragma unroll
    for (int i = 0; i < 8; ++i) {
        float v = x[i];
        _Float16 hv = (_Float16)v;          // RNE
        h[i] = hv;
        l[i] = (_Float16)(v - (float)hv);   // exact residual in f32, RNE to f16
    }
}

__device__ __forceinline__ unsigned int ford(float f) {   // monotone float->uint
    unsigned int b = __float_as_uint(f);
    return (b & 0x80000000u) ? ~b : (b | 0x80000000u);
}

// ---- ws layout (bytes); ws >= 8.4 MB (proven R5-R17) ----
#define WS_C2H   0u          // 8192 f32
#define WS_LC    32768u      // 8192 f32 ||rho_c||
#define WS_CN    65536u      // 8192 f32 ||c||
#define WS_CNT   98304u      // int cnt
#define WS_LIST  98560u
#define WS_CAND  360704u
#define WS_THR   622848u
#define WS_KEYS  917504u
#define WS_BPH   2097152u    // 4 MB h-only lane-ordered fragment image

// ---------------- fused prep: pack frag-image + c2h/lc/cn --------------------
// Image: [halfstep = (kt*4+cp)*2 + h][frag = n*2+j][lane][16B], 1 KB frags.
// Frag (halfstep,f) lane l = g*16+c15 holds h-f16 of code kt*128 + h*64 +
// n*16 + c15, d = cp*64 + j*32 + g*8 .. +7  (A/B identical lane map).
__global__ __launch_bounds__(256) void prep_kernel(const float* __restrict__ cb,
                                                   h16* __restrict__ Bp,
                                                   float* __restrict__ c2h,
                                                   float* __restrict__ lc,
                                                   float* __restrict__ cn) {
    const int tid = blockIdx.x * 256 + threadIdx.x;   // 8192*32
    const int code = tid >> 5;
    const int grp = tid & 31;                         // 8-d group
    float x[8];
    *(float4*)&x[0] = *(const float4*)(cb + (size_t)code * DIM + grp * 8);
    *(float4*)&x[4] = *(const float4*)(cb + (size_t)code * DIM + grp * 8 + 4);
    f16x8 hh;
    float s = 0.f, sr = 0.f;
    #pragma unroll
    for (int i = 0; i < 8; ++i) {
        float v = x[i];
        _Float16 hv = (_Float16)v;
        hh[i] = hv;
        s += v * v;
        float rho = v - (float)hv;
        sr += rho * rho;
    }
    const int kt = code >> 7, c = code & 127;
    const int h = c >> 6, cl = c & 63;
    const int n = cl >> 4, c15 = cl & 15;
    const int cp = grp >> 3, j = (grp >> 2) & 1, g = grp & 3;
    const int lane = g * 16 + c15;
    const size_t off = (((size_t)((kt * 4 + cp) * 2 + h) * 8) + (n * 2 + j)) * 512 + lane * 8;
    *(f16x8*)(Bp + off) = hh;

    #pragma unroll
    for (int o = 16; o > 0; o >>= 1) { s += __shfl_xor(s, o); sr += __shfl_xor(sr, o); }
    if (grp == 0) {
        c2h[code] = 0.5f * s;
        cn[code] = sqrtf(s);
        lc[code] = sqrtf(sr);
    }
}

// ---------------- pass 1: BARRIER-FREE hh scores + per-row top-2 bound -------
// Wave-private 2x8KB LDS ring; 8 global_load_lds (1 KB lane-linear) per
// step; counted vmcnt(8) (next step's loads stay in flight); NO s_barrier
// in the hot loop. Wave tile 32x64 (m2 x n4 of 16x16x32), A pre-split in
// regs. Per-code bound with row-correct norms (fixes R13's latent bug).
__global__ __launch_bounds__(256) void vq_pass1(
    const float* __restrict__ rep, const h16* __restrict__ Bp,
    const float* __restrict__ c2h, const float* __restrict__ lcA,
    const float* __restrict__ cnA, int* __restrict__ cand,
    float* __restrict__ thr) {

    __shared__ __align__(16) h16 lds[4][2][8][512];   // [wave][buf][frag][1KB] = 64 KB

    const int t = threadIdx.x;
    const int lane = t & 63;
    const int c15 = lane & 15;
    const int g = lane >> 4;
    const int w = t >> 6;                 // wave 0..3
    const int rh = w >> 1;                // row half 0/1
    const int h = w & 1;                  // col half 0/1
    const int brow = blockIdx.x * 64;

    // ---- A: h fragments + norms; row-correct copies via shfl ----
    f16x8 ah[2][8];
    float hnr[2][4], rnr[2][4];
    #pragma unroll
    for (int m = 0; m < 2; ++m) {
        const float* ar = rep + (size_t)(brow + rh * 32 + m * 16 + c15) * DIM + g * 8;
        float hs = 0.f, rs = 0.f;
        #pragma unroll
        for (int ch = 0; ch < 8; ++ch) {
            float x[8];
            *(float4*)&x[0] = *(const float4*)(ar + ch * 32);
            *(float4*)&x[4] = *(const float4*)(ar + ch * 32 + 4);
            #pragma unroll
            for (int i = 0; i < 8; ++i) {
                _Float16 hv = (_Float16)x[i];
                ah[m][ch][i] = hv;
                float hf = (float)hv;
                hs += hf * hf;
                float rho = x[i] - hf;
                rs += rho * rho;
            }
        }
        hs += __shfl_xor(hs, 16); hs += __shfl_xor(hs, 32);
        rs += __shfl_xor(rs, 16); rs += __shfl_xor(rs, 32);
        float hn = sqrtf(hs), rn = sqrtf(rs);
        #pragma unroll
        for (int r = 0; r < 4; ++r) {     // C/D rows for this lane are g*4+r
            hnr[m][r] = __shfl(hn, g * 4 + r);
            rnr[m][r] = __shfl(rn, g * 4 + r);
        }
    }

    f32x4 acc[2][4];
    float u1v[2][4], u2v[2][4], Dl[4], Dc[4], D2[4];
    int u1i[2][4];
    #pragma unroll
    for (int m = 0; m < 2; ++m)
        #pragma unroll
        for (int n = 0; n < 4; ++n) {
            #pragma unroll
            for (int r = 0; r < 4; ++r) acc[m][n][r] = 0.f;
            u1v[m][n] = -3.4e38f; u2v[m][n] = -3.4e38f; u1i[m][n] = 0;
        }

    // wave-private staging: 8 x 1 KB lane-linear chunks per step
    auto issueStep = [&](int S, int buf) {
        const h16* src = Bp + ((size_t)(S * 2 + h) * 8) * 512 + lane * 8;
        #pragma unroll
        for (int f = 0; f < 8; ++f)
            __builtin_amdgcn_global_load_lds(
                (const __attribute__((address_space(1))) uint32_t*)(src + f * 512),
                (__attribute__((address_space(3))) uint32_t*)(&lds[w][buf][f][lane * 8]),
                16, 0, 0);
    };

    asm volatile("s_waitcnt vmcnt(0)" ::: "memory");   // drain A loads
    issueStep(0, 0);

    #pragma unroll 1
    for (int kt = 0; kt < NKT; ++kt) {
        const int ktbase = kt * BN;
        #pragma unroll
        for (int cp = 0; cp < 4; ++cp) {            // step S = kt*4+cp
            const int S = kt * 4 + cp;
            const int cur = cp & 1;                 // ring parity (4 even)
            if (cp == 0) {                          // per-kt bound constants
                #pragma unroll
                for (int n = 0; n < 4; ++n) {
                    const int col = ktbase + h * 64 + n * 16 + c15;
                    Dl[n] = lcA[col];
                    Dc[n] = cnA[col];
                    D2[n] = 0.012f - c2h[col];
                }
            }
            if (S + 1 < NSTEP) issueStep(S + 1, cur ^ 1);
            // S's 8 loads are the oldest outstanding; newest 8 = S+1's.
            if (S == NSTEP - 1) asm volatile("s_waitcnt vmcnt(0)" ::: "memory");
            else                asm volatile("s_waitcnt vmcnt(8)" ::: "memory");
            __builtin_amdgcn_sched_barrier(0);      // rule 18

            #pragma unroll
            for (int j = 0; j < 2; ++j) {
                const int ch = cp * 2 + j;          // d-chunk 0..7, static
                #pragma unroll
                for (int n = 0; n < 4; ++n) {
                    f16x8 bh = *(const f16x8*)&lds[w][cur][n * 2 + j][lane * 8];
                    #pragma unroll
                    for (int m = 0; m < 2; ++m)
                        acc[m][n] = __builtin_amdgcn_mfma_f32_16x16x32_f16(ah[m][ch], bh, acc[m][n], 0, 0, 0);
                }
            }

            if (cp == 3) {   // per-kt epilogue: u = acc + row-code bound; top-2
                #pragma unroll
                for (int n = 0; n < 4; ++n) {
                    const int col = ktbase + h * 64 + n * 16 + c15;
                    #pragma unroll
                    for (int m = 0; m < 2; ++m)
                        #pragma unroll
                        for (int r = 0; r < 4; ++r) {
                            float u = fmaf(hnr[m][r], Dl[n],
                                      fmaf(rnr[m][r], Dc[n], acc[m][n][r] + D2[n]));
                            if (u > u1v[m][r]) { u2v[m][r] = u1v[m][r]; u1v[m][r] = u; u1i[m][r] = col; }
                            else if (u > u2v[m][r]) u2v[m][r] = u;
                            acc[m][n][r] = 0.f;
                        }
                }
            }
        }
    }

    // ---- merge top-2 across 16 c15-lanes, then across col-half waves ----
    __syncthreads();   // only barrier: all compute done; lds[0] = scratch
    float* sv1 = (float*)&lds[0][0][0][0];         // [row 0..63][half 0..1]
    int* si1 = (int*)((char*)&lds[0][0][0][0] + 1024);
    float* sv2 = (float*)((char*)&lds[0][0][0][0] + 2048);
    #pragma unroll
    for (int m = 0; m < 2; ++m)
        #pragma unroll
        for (int r = 0; r < 4; ++r) {
            float a1 = u1v[m][r], a2 = u2v[m][r];
            int a1i = u1i[m][r];
            #pragma unroll
            for (int mask = 1; mask <= 8; mask <<= 1) {
                float b1 = __shfl_xor(a1, mask);
                int b1i = __shfl_xor(a1i, mask);
                float b2 = __shfl_xor(a2, mask);
                if (b1 > a1) { a2 = fmaxf(a1, b2); a1 = b1; a1i = b1i; }
                else         { a2 = fmaxf(b1, a2); }
            }
            if (c15 == 0) {
                const int rl = rh * 32 + m * 16 + g * 4 + r;   // 0..63
                sv1[rl * 2 + h] = a1;
                si1[rl * 2 + h] = a1i;
                sv2[rl * 2 + h] = a2;
            }
        }
    __syncthreads();
    if (t < 64) {
        float a1 = sv1[t * 2], a2 = sv2[t * 2];
        int a1i = si1[t * 2];
        float b1 = sv1[t * 2 + 1], b2 = sv2[t * 2 + 1];
        int b1i = si1[t * 2 + 1];
        float u1, u2; int u1idx;
        if (b1 > a1) { u1 = b1; u1idx = b1i; u2 = fmaxf(a1, b2); }
        else         { u1 = a1; u1idx = a1i; u2 = fmaxf(b1, a2); }
        cand[brow + t] = u1idx;
        thr[brow + t] = u2;
    }
}

// ---------------- resolve: exact fp32 score of candidate; safe iff > thr -----
__global__ __launch_bounds__(256) void resolve_kernel(
    const float* __restrict__ rep, const float* __restrict__ cb,
    const float* __restrict__ c2h, const int* __restrict__ cand,
    const float* __restrict__ thr, int* __restrict__ out,
    int* __restrict__ cnt, int* __restrict__ list, int N) {
    const int W = (blockIdx.x * 256 + threadIdx.x) >> 6;
    const int lane = threadIdx.x & 63;
    if (W >= N) return;
    const int ci = cand[W];
    const float4 rv = *(const float4*)(rep + (size_t)W * DIM + lane * 4);
    const float4 cv = *(const float4*)(cb + (size_t)ci * DIM + lane * 4);
    float p = rv.x * cv.x + rv.y * cv.y + rv.z * cv.z + rv.w * cv.w;
    #pragma unroll
    for (int off = 32; off > 0; off >>= 1) p += __shfl_down(p, off);
    if (lane == 0) {
        float sex = p - c2h[ci];
        out[W] = ci;                              // provisional
        if (!(sex > thr[W])) {                    // not provably optimal
            int pos = atomicAdd(cnt, 1);
            list[pos] = W;
        }
    }
}

// ---------------- rescan: (row-group x kt) parallel exact 4-pass tiles -------
__global__ __launch_bounds__(256) void rescan_kernel(
    const float* __restrict__ rep, const float* __restrict__ cb,
    const float* __restrict__ c2h, const int* __restrict__ cnt_p,
    const int* __restrict__ list, unsigned long long* __restrict__ keys) {

    const int cnt = *cnt_p;
    const int base = blockIdx.x * 64;
    if (base >= cnt) return;
    const int nrows = min(64, cnt - base);
    const int ktbase = (int)blockIdx.y * BN;

    __shared__ __align__(16) h16 lds[2][BN * 64];
    const int t = threadIdx.x;
    const int lane = t & 63;
    const int w = t >> 6;
    const int c15 = lane & 15;
    const int g = lane >> 4;
    const int wrow = w * 16;

    const int aslot = wrow + c15;
    const int grow = list[base + (aslot < nrows ? aslot : 0)];
    f16x8 ah[8], al[8];
    {
        const float* ar = rep + (size_t)grow * DIM + g * 8;
        #pragma unroll
        for (int ch = 0; ch < 8; ++ch) {
            float x[8];
            *(float4*)&x[0] = *(const float4*)(ar + ch * 32);
            *(float4*)&x[4] = *(const float4*)(ar + ch * 32 + 4);
            split8(x, ah[ch], al[ch]);
        }
    }
    f32x4 acc[8];
    float cc[8];
    #pragma unroll
    for (int n = 0; n < 8; ++n) {
        #pragma unroll
        for (int r = 0; r < 4; ++r) acc[n][r] = 0.f;
        cc[n] = c2h[ktbase + n * 16 + c15];
    }

    const int scol = t >> 1;
    const int dslot = t & 1;
    float breg[16];
    auto loadB = [&](int ch) {
        const float* src = cb + (size_t)(ktbase + scol) * DIM + ch * 32 + dslot * 16;
        #pragma unroll
        for (int i = 0; i < 4; ++i) *(float4*)&breg[i * 4] = *(const float4*)(src + i * 4);
    };
    auto writeB = [&](int buf) {
        #pragma unroll
        for (int half = 0; half < 2; ++half) {
            f16x8 hh, ll;
            split8(&breg[half * 8], hh, ll);
            const int s = dslot * 2 + half;
            *(f16x8*)&lds[buf][scol * 64 + ((s ^ (scol & 7)) << 3)] = hh;
            *(f16x8*)&lds[buf][scol * 64 + (((s + 4) ^ (scol & 7)) << 3)] = ll;
        }
    };

    loadB(0);
    writeB(0);
    loadB(1);
    __syncthreads();

    #pragma unroll
    for (int chunk = 0; chunk < 8; ++chunk) {
        const int buf = chunk & 1;
        if (chunk != 7) writeB(buf ^ 1);
        if (chunk <= 5) loadB(chunk + 2);
        #pragma unroll
        for (int n = 0; n < 8; ++n) {
            const int bb = (n * 16 + c15) * 64;
            f16x8 bh = *(const f16x8*)&lds[buf][bb + ((g ^ (lane & 7)) << 3)];
            f16x8 bl = *(const f16x8*)&lds[buf][bb + (((4 + g) ^ (lane & 7)) << 3)];
            acc[n] = __builtin_amdgcn_mfma_f32_16x16x32_f16(ah[chunk], bh, acc[n], 0, 0, 0);
            acc[n] = __builtin_amdgcn_mfma_f32_16x16x32_f16(ah[chunk], bl, acc[n], 0, 0, 0);
            acc[n] = __builtin_amdgcn_mfma_f32_16x16x32_f16(al[chunk], bh, acc[n], 0, 0, 0);
            acc[n] = __builtin_amdgcn_mfma_f32_16x16x32_f16(al[chunk], bl, acc[n], 0, 0, 0);
        }
        __syncthreads();
    }

    #pragma unroll
    for (int r = 0; r < 4; ++r) {
        float bv = -3.4e38f;
        int bi = 0;
        #pragma unroll
        for (int n = 0; n < 8; ++n) {
            float s2 = acc[n][r] - cc[n];
            const int col = ktbase + n * 16 + c15;
            if (s2 > bv) { bv = s2; bi = col; }
        }
        #pragma unroll
        for (int mask = 1; mask <= 8; mask <<= 1) {
            float ov = __shfl_xor(bv, mask);
            int oi = __shfl_xor(bi, mask);
            if (ov > bv || (ov == bv && oi < bi)) { bv = ov; bi = oi; }
        }
        const int oslot = wrow + g * 4 + r;
        if (c15 == 0 && oslot < nrows) {
            unsigned long long key =
                ((unsigned long long)ford(bv) << 32) | (unsigned int)(~(unsigned int)bi);
            atomicMax(&keys[list[base + oslot]], key);
        }
    }
}

// ---------------- writeback listed rows from merged keys ----------------
__global__ __launch_bounds__(256) void writeback_kernel(
    const int* __restrict__ cnt_p, const int* __restrict__ list,
    const unsigned long long* __restrict__ keys, int* __restrict__ out) {
    int i = blockIdx.x * 256 + threadIdx.x;
    if (i >= *cnt_p) return;
    int row = list[i];
    out[row] = (int)(~(unsigned int)(keys[row] & 0xFFFFFFFFull));
}

extern "C" void kernel_launch(void* const* d_in, const int* in_sizes, int n_in,
                              void* d_out, int out_size, void* d_ws, size_t ws_size,
                              hipStream_t stream) {
    const float* rep = (const float*)d_in[0];
    const float* cb = (const float*)d_in[1];
    const int N = in_sizes[0] / DIM;   // 65536
    const int K = in_sizes[1] / DIM;   // 8192
    (void)K;
    char* ws = (char*)d_ws;
    float* c2h = (float*)(ws + WS_C2H);
    float* lc  = (float*)(ws + WS_LC);
    float* cn  = (float*)(ws + WS_CN);
    int* cnt   = (int*)(ws + WS_CNT);
    int* list  = (int*)(ws + WS_LIST);
    int* cand  = (int*)(ws + WS_CAND);
    float* thr = (float*)(ws + WS_THR);
    unsigned long long* keys = (unsigned long long*)(ws + WS_KEYS);
    h16* Bph   = (h16*)(ws + WS_BPH);
    int* out = (int*)d_out;

    hipMemsetAsync(ws + WS_CNT, 0, 64, stream);
    hipMemsetAsync(keys, 0, (size_t)N * sizeof(unsigned long long), stream);
    prep_kernel<<<dim3(KCODES * 32 / 256), dim3(256), 0, stream>>>(cb, Bph, c2h, lc, cn);
    vq_pass1<<<dim3(N / 64), dim3(256), 0, stream>>>(rep, Bph, c2h, lc, cn, cand, thr);
    resolve_kernel<<<dim3(N / 4), dim3(256), 0, stream>>>(rep, cb, c2h, cand, thr, out, cnt, list, N);
    rescan_kernel<<<dim3(N / 64, NKT), dim3(256), 0, stream>>>(rep, cb, c2h, cnt, list, keys);
    writeback_kernel<<<dim3(N / 256), dim3(256), 0, stream>>>(cnt, list, keys, out);
}